// Round 2
// baseline (705.779 us; speedup 1.0000x reference)
//
#include <hip/hip_runtime.h>

// Sub_MGU: B=64, T=2048, S=32, H=16. 2048 independent serial sequences.
// Wave = 4 cells (same b, 4 consecutive s); lane (sl,j) owns h[j] and weight
// rows W_hhf/W_hhn[s][j][:] in VGPRs.
//
// R3/R4 change vs R2 (latency-bound at ~540 cyc/step, VALUBusy 14.5%):
//  - h exchange via 15x v_mov_b32 DPP row_ror:1..15 (VALU pipe, ~4-8 cyc
//    latency each, independent) instead of 16x ds_swizzle (LDS pipe,
//    ~120+ cyc latency on the serial h->matvec chain). The per-lane
//    rotation order is discovered at init by pushing an integer lane-id
//    probe through the SAME DPP network; weights are gathered in that
//    permuted order, so the dot product is correct regardless of ror
//    direction convention.
//  - exp2 argument scales folded into weights/biases at init:
//    wf/wif/bf *= -log2e, wn/win/bin/bhn *= 2*log2e — removes 2 serial
//    v_mul from the per-step nonlinear chain.
//  - n - h computed as fma(-2, r, omh) with omh = 1-h precomputed off the
//    critical path at the end of the previous step.
//  - x prefetched 8 steps deep in a register ring (unchanged).
// (R4 == R3 resubmitted: round-1 bench died with a container-level infra
//  error, no kernel diagnostic.)

#define TT 2048
#define SS 32
#define HH 16

// DPP row_ror:R within each 16-lane row. ctrl = 0x120 + R (R>=1).
template <int R>
__device__ __forceinline__ void bcast_ror(int hi, float* u) {
    u[R] = __int_as_float(
        __builtin_amdgcn_update_dpp(hi, hi, 0x120 + R, 0xF, 0xF, false));
    if constexpr (R + 1 < 16) bcast_ror<R + 1>(hi, u);
}

// Same network applied to an integer lane-id probe: k[r] = source lane of
// slot r (direction-proof weight permutation discovery).
template <int R>
__device__ __forceinline__ void probe_ror(int jj, int* k) {
    k[R] = __builtin_amdgcn_update_dpp(jj, jj, 0x120 + R, 0xF, 0xF, false);
    if constexpr (R + 1 < 16) probe_ror<R + 1>(jj, k);
}

__global__ __launch_bounds__(64) void mgu_kernel(
    const float* __restrict__ input,   // [B, T, S]
    const float* __restrict__ W_hif,   // [S, H]
    const float* __restrict__ W_hin,   // [S, H]
    const float* __restrict__ W_hhf,   // [S, H, H]
    const float* __restrict__ W_hhn,   // [S, H, H]
    const float* __restrict__ bias_hi, // [2*S*H]
    const float* __restrict__ bias_hh, // [2*S*H]
    float* __restrict__ out)           // [B, T, S*H]
{
    const int lane = threadIdx.x;      // 0..63
    const int sl   = lane >> 4;        // cell within wave (0..3)
    const int b    = blockIdx.x & 63;  // batch index — same-b blocks adjacent
    const int sg   = blockIdx.x >> 6;  // subunit group (0..7)
    const int s    = sg * 4 + sl;      // subunit (0..31)
    const int j    = lane & 15;
    const int row  = s * HH + j;

    const float NL2E = -1.442695041f;  // -log2(e)
    const float TL2E =  2.885390082f;  // 2*log2(e)

    // ---- discover the DPP ror lane->slot mapping ----
    int kidx[16];
    kidx[0] = j;
    probe_ror<1>(j, kidx);

    // ---- preload weight rows, permuted to match the DPP slot order, with
    // exp2 scale constants folded in ----
    float wf[16], wn[16];
    {
        const float* Wfr = W_hhf + row * HH;
        const float* Wnr = W_hhn + row * HH;
#pragma unroll
        for (int r = 0; r < 16; ++r) {
            wf[r] = Wfr[kidx[r]] * NL2E;
            wn[r] = Wnr[kidx[r]] * TL2E;
        }
    }
    const float wifp = W_hif[row] * NL2E;
    const float winp = W_hin[row] * TL2E;
    const float bfp  = (bias_hi[row] + bias_hh[row]) * NL2E;  // folded forget biases
    const float binp = bias_hi[SS * HH + row] * TL2E;
    const float bhnp = bias_hh[SS * HH + row] * TL2E;

    const float* xp = input + (size_t)b * (TT * SS) + s;
    float*       op = out   + (size_t)b * (TT * SS * HH) + sg * 64 + lane;

    // ---- 8-deep x prefetch ring (covers HBM latency at ~150cyc/step x 8) ----
    float xbuf[8];
#pragma unroll
    for (int i = 0; i < 8; ++i) xbuf[i] = xp[i * SS];

    float h = 0.0f, omh = 1.0f;   // omh = 1 - h, maintained off critical path

#pragma unroll 1
    for (int t = 0; t < TT; t += 8) {
#pragma unroll
        for (int p = 0; p < 8; ++p) {
            const float x = xbuf[p];
            // refill slot p for step t+p+8 (clamped tail; harmless reload)
            int tf = t + p + 8; tf = (tf < TT) ? tf : (TT - 1);
            xbuf[p] = xp[(size_t)tf * SS];

            // ---- h exchange: 15x DPP row_ror within 16-lane cell (VALU) ----
            float u[16];
            u[0] = h;
            bcast_ror<1>(__float_as_int(h), u);

            // ---- dual matvecs, even/odd split: 4 independent 8-deep chains,
            // weights pre-permuted to DPP slot order and pre-scaled ----
            float accf0 = __builtin_fmaf(x, wifp, bfp), accf1 = 0.0f;
            float accn0 = bhnp,                         accn1 = 0.0f;
#pragma unroll
            for (int k = 0; k < 8; ++k) {
                accf0 = __builtin_fmaf(wf[2*k],   u[2*k],   accf0);
                accf1 = __builtin_fmaf(wf[2*k+1], u[2*k+1], accf1);
                accn0 = __builtin_fmaf(wn[2*k],   u[2*k],   accn0);
                accn1 = __builtin_fmaf(wn[2*k+1], u[2*k+1], accn1);
            }
            const float accf = accf0 + accf1;   // = -log2e * (linear forget preact)
            const float accn = accn0 + accn1;   // = 2log2e * (recurrent new preact)

            // f = sigmoid(lin_f) = rcp(1 + exp2(accf))
            const float f = __builtin_amdgcn_rcpf(
                1.0f + __builtin_amdgcn_exp2f(accf));
            // y = 2log2e * (i_n + f*accn_lin); n = tanh = 1 - 2*rcp(1+exp2(y))
            const float inp = __builtin_fmaf(x, winp, binp);
            const float y   = __builtin_fmaf(f, accn, inp);
            const float rr  = __builtin_amdgcn_rcpf(
                1.0f + __builtin_amdgcn_exp2f(y));
            const float nmh = __builtin_fmaf(-2.0f, rr, omh);  // n - h
            h   = __builtin_fmaf(f, nmh, h);                   // h += f*(n-h)
            omh = 1.0f - h;

            op[(size_t)(t + p) * (SS * HH)] = h;
        }
    }
}

extern "C" void kernel_launch(void* const* d_in, const int* in_sizes, int n_in,
                              void* d_out, int out_size, void* d_ws, size_t ws_size,
                              hipStream_t stream) {
    const float* input   = (const float*)d_in[0];
    const float* W_hif   = (const float*)d_in[1];
    const float* W_hin   = (const float*)d_in[2];
    const float* W_hhf   = (const float*)d_in[3];
    const float* W_hhn   = (const float*)d_in[4];
    const float* bias_hi = (const float*)d_in[5];
    const float* bias_hh = (const float*)d_in[6];
    float* out = (float*)d_out;

    mgu_kernel<<<dim3(512), dim3(64), 0, stream>>>(
        input, W_hif, W_hin, W_hhf, W_hhn, bias_hi, bias_hh, out);
}

// Round 3
// 561.539 us; speedup vs baseline: 1.2569x; 1.2569x over previous
//
#include <hip/hip_runtime.h>

// Sub_MGU: B=64, T=2048, S=32, H=16. 2048 independent serial sequences.
// Wave = 4 cells (same b, 4 consecutive s); lane (sl,j) owns h[j] and weight
// rows W_hhf/W_hhn[s][j][:] in VGPRs.
//
// R5 change vs R3/R4 (dispatch 484us, VALUBusy 23.5% == exact issue count ->
// ~434 cyc/step stall common to swizzle AND DPP versions):
//  THEORY: the per-step global_store reads its data VGPR after issue; h (the
//  store source) is the loop-carried register redefined next step, so the
//  compiler inserts a vmcnt wait per step that drains the previous store
//  (~400 cyc L2/HBM ack) AND the older prefetch loads. Fix:
//  - store from an opaque v_mov snapshot (inline asm -> cannot be coalesced
//    with h), 16 snapshots kept alive to block end -> store-data physregs
//    redefined 16 steps (~2500 cyc) after the store read them -> WAR wait
//    becomes vmcnt(~31) == free.
//  - x prefetch ring deepened to 16 (covers ~900cyc HBM-miss at the faster
//    step time); tail handled by a no-refill block instead of per-step clamp.
//  - matvec chains split 4-way (4 x 4-deep FMA + 2 adds, was 2 x 8-deep).
// Carried from R3: DPP row_ror h-exchange (VALU pipe), exp2 scales folded
// into weights/biases, omh=1-h maintained off the critical path.

#define TT 2048
#define SS 32
#define HH 16

// DPP row_ror:R within each 16-lane row. ctrl = 0x120 + R (R>=1).
template <int R>
__device__ __forceinline__ void bcast_ror(int hi, float* u) {
    u[R] = __int_as_float(
        __builtin_amdgcn_update_dpp(hi, hi, 0x120 + R, 0xF, 0xF, false));
    if constexpr (R + 1 < 16) bcast_ror<R + 1>(hi, u);
}

// Same network applied to an integer lane-id probe: k[r] = source lane of
// slot r (direction-proof weight permutation discovery).
template <int R>
__device__ __forceinline__ void probe_ror(int jj, int* k) {
    k[R] = __builtin_amdgcn_update_dpp(jj, jj, 0x120 + R, 0xF, 0xF, false);
    if constexpr (R + 1 < 16) probe_ror<R + 1>(jj, k);
}

template <bool REFILL>
__device__ __forceinline__ void block16(
    float& h, float& omh, float (&xbuf)[16],
    const float* xq, float* opq,
    const float (&wf)[16], const float (&wn)[16],
    float wifp, float winp, float bfp, float binp, float bhnp)
{
    float hs[16];
#pragma unroll
    for (int p = 0; p < 16; ++p) {
        const float x = xbuf[p];
        if constexpr (REFILL) xbuf[p] = xq[p * SS];  // refill for step q+16

        // ---- h exchange: 15x DPP row_ror within 16-lane cell (VALU) ----
        float u[16];
        u[0] = h;
        bcast_ror<1>(__float_as_int(h), u);

        // ---- dual matvecs, 4-way split: 8 independent 4-deep FMA chains ----
        float a0 = __builtin_fmaf(x, wifp, bfp), a1 = 0.0f, a2 = 0.0f, a3 = 0.0f;
        float c0 = bhnp, c1 = 0.0f, c2 = 0.0f, c3 = 0.0f;
#pragma unroll
        for (int kk = 0; kk < 4; ++kk) {
            a0 = __builtin_fmaf(wf[4*kk+0], u[4*kk+0], a0);
            a1 = __builtin_fmaf(wf[4*kk+1], u[4*kk+1], a1);
            a2 = __builtin_fmaf(wf[4*kk+2], u[4*kk+2], a2);
            a3 = __builtin_fmaf(wf[4*kk+3], u[4*kk+3], a3);
            c0 = __builtin_fmaf(wn[4*kk+0], u[4*kk+0], c0);
            c1 = __builtin_fmaf(wn[4*kk+1], u[4*kk+1], c1);
            c2 = __builtin_fmaf(wn[4*kk+2], u[4*kk+2], c2);
            c3 = __builtin_fmaf(wn[4*kk+3], u[4*kk+3], c3);
        }
        const float accf = (a0 + a1) + (a2 + a3);  // -log2e * forget preact
        const float accn = (c0 + c1) + (c2 + c3);  // 2log2e * recurrent new preact

        // f = sigmoid = rcp(1 + exp2(accf)) ; n = tanh = 1 - 2*rcp(1+exp2(y))
        const float f   = __builtin_amdgcn_rcpf(1.0f + __builtin_amdgcn_exp2f(accf));
        const float inp = __builtin_fmaf(x, winp, binp);
        const float y   = __builtin_fmaf(f, accn, inp);
        const float rr  = __builtin_amdgcn_rcpf(1.0f + __builtin_amdgcn_exp2f(y));
        const float nmh = __builtin_fmaf(-2.0f, rr, omh);  // n - h
        h   = __builtin_fmaf(f, nmh, h);                   // h += f*(n-h)
        omh = 1.0f - h;

        // Opaque snapshot: store-data reg is NOT the recurrence reg.
        asm volatile("v_mov_b32 %0, %1" : "=v"(hs[p]) : "v"(h));
        opq[(size_t)p * (SS * HH)] = hs[p];
    }
    // Keep all 16 store-data registers live to block end: each physreg is
    // redefined only one full block (16 steps ~ 2500 cyc) after its store
    // read it -> the compiler's WAR vmcnt wait is trivially satisfied.
    asm volatile("" ::
        "v"(hs[0]),  "v"(hs[1]),  "v"(hs[2]),  "v"(hs[3]),
        "v"(hs[4]),  "v"(hs[5]),  "v"(hs[6]),  "v"(hs[7]),
        "v"(hs[8]),  "v"(hs[9]),  "v"(hs[10]), "v"(hs[11]),
        "v"(hs[12]), "v"(hs[13]), "v"(hs[14]), "v"(hs[15]));
}

__global__ __launch_bounds__(64) void mgu_kernel(
    const float* __restrict__ input,   // [B, T, S]
    const float* __restrict__ W_hif,   // [S, H]
    const float* __restrict__ W_hin,   // [S, H]
    const float* __restrict__ W_hhf,   // [S, H, H]
    const float* __restrict__ W_hhn,   // [S, H, H]
    const float* __restrict__ bias_hi, // [2*S*H]
    const float* __restrict__ bias_hh, // [2*S*H]
    float* __restrict__ out)           // [B, T, S*H]
{
    const int lane = threadIdx.x;      // 0..63
    const int sl   = lane >> 4;        // cell within wave (0..3)
    const int b    = blockIdx.x & 63;  // batch index — same-b blocks adjacent
    const int sg   = blockIdx.x >> 6;  // subunit group (0..7)
    const int s    = sg * 4 + sl;      // subunit (0..31)
    const int j    = lane & 15;
    const int row  = s * HH + j;

    const float NL2E = -1.442695041f;  // -log2(e)
    const float TL2E =  2.885390082f;  // 2*log2(e)

    // ---- discover the DPP ror lane->slot mapping ----
    int kidx[16];
    kidx[0] = j;
    probe_ror<1>(j, kidx);

    // ---- preload weight rows, permuted to DPP slot order, scales folded ----
    float wf[16], wn[16];
    {
        const float* Wfr = W_hhf + row * HH;
        const float* Wnr = W_hhn + row * HH;
#pragma unroll
        for (int r = 0; r < 16; ++r) {
            wf[r] = Wfr[kidx[r]] * NL2E;
            wn[r] = Wnr[kidx[r]] * TL2E;
        }
    }
    const float wifp = W_hif[row] * NL2E;
    const float winp = W_hin[row] * TL2E;
    const float bfp  = (bias_hi[row] + bias_hh[row]) * NL2E;  // folded forget biases
    const float binp = bias_hi[SS * HH + row] * TL2E;
    const float bhnp = bias_hh[SS * HH + row] * TL2E;

    const float* xp = input + (size_t)b * (TT * SS) + s;
    float*       op = out   + (size_t)b * (TT * SS * HH) + sg * 64 + lane;

    // ---- 16-deep x prefetch ring ----
    float xbuf[16];
#pragma unroll
    for (int i = 0; i < 16; ++i) xbuf[i] = xp[i * SS];

    float h = 0.0f, omh = 1.0f;   // omh = 1 - h, maintained off critical path

#pragma unroll 1
    for (int t = 0; t < TT - 16; t += 16) {
        block16<true>(h, omh, xbuf,
                      xp + (size_t)(t + 16) * SS,
                      op + (size_t)t * (SS * HH),
                      wf, wn, wifp, winp, bfp, binp, bhnp);
    }
    // Tail: last 16 steps consume the ring, no refill (no clamp math needed).
    block16<false>(h, omh, xbuf,
                   xp,  // unused
                   op + (size_t)(TT - 16) * (SS * HH),
                   wf, wn, wifp, winp, bfp, binp, bhnp);
}

extern "C" void kernel_launch(void* const* d_in, const int* in_sizes, int n_in,
                              void* d_out, int out_size, void* d_ws, size_t ws_size,
                              hipStream_t stream) {
    const float* input   = (const float*)d_in[0];
    const float* W_hif   = (const float*)d_in[1];
    const float* W_hin   = (const float*)d_in[2];
    const float* W_hhf   = (const float*)d_in[3];
    const float* W_hhn   = (const float*)d_in[4];
    const float* bias_hi = (const float*)d_in[5];
    const float* bias_hh = (const float*)d_in[6];
    float* out = (float*)d_out;

    mgu_kernel<<<dim3(512), dim3(64), 0, stream>>>(
        input, W_hif, W_hin, W_hhf, W_hhn, bias_hi, bias_hh, out);
}